// Round 13
// baseline (270.683 us; speedup 1.0000x reference)
//
#include <hip/hip_runtime.h>
#include <cstdint>
#include <cstddef>

// Problem constants
#define T_TOK 8192
#define K_CODE 8192
#define C_DIM 512
#define BETA 0.25f
#define DECAY 0.99f
#define ONE_MINUS_DECAY 0.01f
#define EPS_F 1e-5f
#define K_EPS 0.08192f
// Coarse-dist error: f16 GEMM bound 0.025 + key quantization 2*0.002;
// sufficiency needs MARGIN > 2*(E1+eq) = 0.054 -> 0.0625 still conservative.
#define MARGIN 0.0625f

// d_out layout (floats, concatenated in reference return order)
#define ZQ_OFF   ((size_t)0)          // z_q_st      [8,1024,512] = 4194304
#define IDX_OFF  ((size_t)4194304)    // indices     [8,1024]     = 8192
#define LOSS_OFF ((size_t)4202496)    // vq_loss     scalar       = 1
#define NCB_OFF  ((size_t)4202497)    // new_codebook[8192,512]   = 4194304
#define NCS_OFF  ((size_t)8396801)    // new_cluster [8192]       = 8192
#define NEA_OFF  ((size_t)8404993)    // new_embed_avg[8192,512]  = 4194304

// Transient regions (all stream-ordered, lifetime-checked):
//   zp f16 = floats [0, 2097152); cp f16 = floats [2097152, 4194304) —
//     both dead after dist (refine then writes ZQ over them).
//   slab1/slab2 u32[8192*64] each at [8404994, 9453570) — transposed [t][bn];
//     written by dist, read by refine, dead before NEA writes.
//   lossP f32[8192] at [9453570, 9461762) — written by refine (plain stores;
//     MUST stay outside ZQ — round-6 race), read by scan_ncs_scatter, dead
//     before NEA writes.
//   list/offsB: in d_ws when ws_size permits (enables merged
//     percode_finalize, which writes NEA without racing them); else in out
//     after lossP (fallback: percode/finalize stay SPLIT because finalize's
//     NEA write would clobber live list rows ~4096-4127).
#define CP_F_OFF    ((size_t)2097152)
#define SLAB1_F_OFF ((size_t)8404994)
#define SLAB2_F_OFF ((size_t)(8404994 + 524288))
#define LOSSP_F_OFF ((size_t)9453570)
#define LIST_I_OFF  ((size_t)10502146)
#define OFFSB_I_OFF ((size_t)10518530)

// d_ws layout (float offsets)
#define WS_ZNORM  0
#define WS_ENORM  8192
#define WS_ICOUNT 16384   // int[8192]
#define WS_NSUM   24576
#define WS_LIST   24608   // int[8192]  (only if ws_size >= 163968 B)
#define WS_OFFSB  32800   // int[8192]
#define WS_NEED_BYTES ((size_t)(32800 + 8192) * 4)

typedef _Float16 half8 __attribute__((ext_vector_type(8)));
typedef _Float16 half4v __attribute__((ext_vector_type(4)));
typedef float floatx4 __attribute__((ext_vector_type(4)));
typedef unsigned long long ull;

__device__ __forceinline__ void gload16(const void* g, void* l) {
    __builtin_amdgcn_global_load_lds(
        (const __attribute__((address_space(1))) void*)g,
        (__attribute__((address_space(3))) void*)l, 16, 0, 0);
}

__device__ __forceinline__ unsigned umin32(unsigned a, unsigned b) { return a < b ? a : b; }
__device__ __forceinline__ unsigned umax32(unsigned a, unsigned b) { return a > b ? a : b; }
__device__ __forceinline__ ull umin64(ull a, ull b) { return a < b ? a : b; }

__device__ inline ull shfl_xor_u64(ull v, int m) {
    int lo = (int)(unsigned)(v & 0xFFFFFFFFull);
    int hi = (int)(unsigned)(v >> 32);
    lo = __shfl_xor(lo, m, 64);
    hi = __shfl_xor(hi, m, 64);
    return ((ull)(unsigned)hi << 32) | (unsigned)lo;
}

__device__ __forceinline__ float dot8(float4 z0, float4 z1, float4 c0, float4 c1) {
    float p = 0.0f;
    p = fmaf(z0.x, c0.x, p); p = fmaf(z0.y, c0.y, p);
    p = fmaf(z0.z, c0.z, p); p = fmaf(z0.w, c0.w, p);
    p = fmaf(z1.x, c1.x, p); p = fmaf(z1.y, c1.y, p);
    p = fmaf(z1.z, c1.z, p); p = fmaf(z1.w, c1.w, p);
    return p;
}

// ---- K1: f16 convert pack + row norms + icount zeroing ----------------------
__global__ __launch_bounds__(256) void prep_kernel(const float* __restrict__ z,
                                                   const float* __restrict__ cb,
                                                   _Float16* __restrict__ zp,
                                                   _Float16* __restrict__ cp,
                                                   float* __restrict__ ws,
                                                   int* __restrict__ icount) {
    int tid = threadIdx.x;
    if (blockIdx.x < 32) icount[blockIdx.x * 256 + tid] = 0;  // replaces memset launch
    int row = blockIdx.x * 2 + (tid >> 7);   // 0..16383
    int l128 = tid & 127;
    const float* src;
    _Float16* dst;
    float* nrm;
    if (row < T_TOK) { src = z + (size_t)row * C_DIM; dst = zp + (size_t)row * C_DIM; nrm = ws + WS_ZNORM + row; }
    else { int r = row - T_TOK; src = cb + (size_t)r * C_DIM; dst = cp + (size_t)r * C_DIM; nrm = ws + WS_ENORM + r; }
    float4 v = *(const float4*)(src + l128 * 4);
    half4v h;
    h[0] = (_Float16)v.x; h[1] = (_Float16)v.y;
    h[2] = (_Float16)v.z; h[3] = (_Float16)v.w;
    *(half4v*)(dst + l128 * 4) = h;          // 8 B packed store
    float s = v.x * v.x + v.y * v.y + v.z * v.z + v.w * v.w;
    #pragma unroll
    for (int m = 32; m; m >>= 1) s += __shfl_down(s, m, 64);
    __shared__ float red[4];
    if ((tid & 63) == 0) red[tid >> 6] = s;
    __syncthreads();
    if ((tid & 127) == 0) nrm[0] = red[tid >> 6] + red[(tid >> 6) + 1];
}

// ---- K2: coarse f16 MFMA GEMM (K=512) + per-slice top-2 slab ----------------
// Round-10 structure (118.4 µs) + __launch_bounds__(256, 4): forces combined
// reg file <= 128/wave (was 76 VGPR + 64 AGPR = 140 -> 3 waves/SIMD, occ 30%).
// If the allocator shaves ~12 arch-VGPRs without spilling, 4 blocks/CU become
// co-resident -> +33% latency-hiding over the per-K-step vmcnt(0) drains at
// CONSTANT tile/barrier structure (r11's occupancy test was confounded by
// halving MFMA-per-barrier; this isolates occupancy alone).
__global__ __launch_bounds__(256, 4) void dist_mfma_kernel(
        const _Float16* __restrict__ zp, const _Float16* __restrict__ cp,
        const float* __restrict__ znorm, const float* __restrict__ enorm,
        unsigned* __restrict__ slab1, unsigned* __restrict__ slab2) {
    __shared__ __align__(16) _Float16 As[128 * 32];
    __shared__ __align__(16) _Float16 Bs[128 * 32];
    __shared__ unsigned red2[128][2][2];
    const int tid = threadIdx.x;
    const int w = tid >> 6, lane = tid & 63;
    const int quad = lane >> 4, lr = lane & 15;
    const int wm = w >> 1, wn = w & 1;

    const int GRID_N = 64, GROUP_M = 16;
    int pid0 = blockIdx.x;
    int pid = (pid0 & 7) * 512 + (pid0 >> 3);   // XCD swizzle: 4096/8 = 512
    int per = GROUP_M * GRID_N;
    int g = pid / per;
    int local = pid % per;
    int bm = g * GROUP_M + (local & (GROUP_M - 1));
    int bn = local / GROUP_M;
    const int mBase = bm * 128, nBase = bn * 128;

    int r0 = (w * 2 + 0) * 16 + (lane >> 2);
    int r1 = (w * 2 + 1) * 16 + (lane >> 2);
    int cq = (((lane & 3) ^ ((lane >> 3) & 3))) * 8;
    const _Float16* ga0 = zp + (size_t)(mBase + r0) * C_DIM + cq;
    const _Float16* ga1 = zp + (size_t)(mBase + r1) * C_DIM + cq;
    const _Float16* gb0 = cp + (size_t)(nBase + r0) * C_DIM + cq;
    const _Float16* gb1 = cp + (size_t)(nBase + r1) * C_DIM + cq;
    _Float16* la0 = As + (w * 2 + 0) * 512;
    _Float16* la1 = As + (w * 2 + 1) * 512;
    _Float16* lb0 = Bs + (w * 2 + 0) * 512;
    _Float16* lb1 = Bs + (w * 2 + 1) * 512;

    const int slotA = (quad ^ ((lr >> 1) & 3)) * 8;
    const _Float16* aFrag = As + ((size_t)(wm * 64 + lr)) * 32 + slotA;
    const _Float16* bFrag = Bs + ((size_t)(wn * 64 + lr)) * 32 + slotA;

    floatx4 acc[4][4] = {};

    for (int it = 0; it < 16; ++it) {
        __syncthreads();
        gload16(ga0, la0);
        gload16(ga1, la1);
        gload16(gb0, lb0);
        gload16(gb1, lb1);
        ga0 += 32; ga1 += 32; gb0 += 32; gb1 += 32;
        __syncthreads();
        half8 af[4], bf[4];
        #pragma unroll
        for (int i = 0; i < 4; ++i) af[i] = *(const half8*)(aFrag + i * 16 * 32);
        #pragma unroll
        for (int j = 0; j < 4; ++j) bf[j] = *(const half8*)(bFrag + j * 16 * 32);
        #pragma unroll
        for (int i = 0; i < 4; ++i)
            #pragma unroll
            for (int j = 0; j < 4; ++j)
                acc[i][j] = __builtin_amdgcn_mfma_f32_16x16x32_f16(af[i], bf[j], acc[i][j], 0, 0, 0);
    }

    float en[4];
    #pragma unroll
    for (int j = 0; j < 4; ++j) en[j] = enorm[nBase + wn * 64 + j * 16 + lr];
    #pragma unroll
    for (int i = 0; i < 4; ++i) {
        #pragma unroll
        for (int r = 0; r < 4; ++r) {
            int lrow = wm * 64 + i * 16 + quad * 4 + r;
            float zn = znorm[mBase + lrow];
            unsigned t1 = 0xFFFFFFFFu, t2 = 0xFFFFFFFFu;
            #pragma unroll
            for (int j = 0; j < 4; ++j) {
                int nLoc = wn * 64 + j * 16 + lr;            // 0..127 within slice
                float s = (zn - 2.0f * acc[i][j][r]) + en[j];
                s = fmaxf(s, 0.0f);                          // keep uint ordering valid
                unsigned key = ((__float_as_uint(s) + 0x40u) & 0xFFFFFF80u) | (unsigned)nLoc;
                if (key < t1) { t2 = t1; t1 = key; } else if (key < t2) t2 = key;
            }
            #pragma unroll
            for (int msk = 1; msk < 16; msk <<= 1) {
                unsigned o1 = (unsigned)__shfl_xor((int)t1, msk, 64);
                unsigned o2 = (unsigned)__shfl_xor((int)t2, msk, 64);
                unsigned n1 = umin32(t1, o1);
                unsigned n2 = umin32(umax32(t1, o1), umin32(t2, o2));
                t1 = n1; t2 = n2;
            }
            if (lr == 0) { red2[lrow][wn][0] = t1; red2[lrow][wn][1] = t2; }
        }
    }
    __syncthreads();
    if (tid < 128) {
        unsigned a1 = red2[tid][0][0], a2 = red2[tid][0][1];
        unsigned b1 = red2[tid][1][0], b2 = red2[tid][1][1];
        unsigned m1 = umin32(a1, b1);
        unsigned m2 = umin32(umax32(a1, b1), umin32(a2, b2));
        slab1[(size_t)(mBase + tid) * 64 + bn] = m1;   // transposed [t][bn]
        slab2[(size_t)(mBase + tid) * 64 + bn] = m2;
    }
}

// ---- K3: refine + fused gather --------------------------------------------
// One WAVE per token; 16-lane-GROUP dot products (each group owns one
// candidate; z chunked per-lane). UNCHANGED (control).
__global__ __launch_bounds__(256) void refine_gather_kernel(
        const float* __restrict__ z, const float* __restrict__ cb,
        const float* __restrict__ znorm, const float* __restrict__ enorm,
        const unsigned* __restrict__ slab1, const unsigned* __restrict__ slab2,
        float* __restrict__ out, int* __restrict__ icount,
        float* __restrict__ lossP) {
    int tid = threadIdx.x;
    int wv = tid >> 6, lane = tid & 63;
    int grp = lane >> 4, gl = lane & 15;
    int t = blockIdx.x * 4 + wv;

    unsigned s1 = slab1[(size_t)t * 64 + lane];      // coalesced: 64 x u32
    unsigned s2 = slab2[(size_t)t * 64 + lane];
    const float* zr = z + (size_t)t * C_DIM;
    float4 z0 = *(const float4*)(zr + lane * 8);
    float4 z1 = *(const float4*)(zr + lane * 8 + 4);
    // chunked z copy for group dots: chunk c covers cols [c*128, c*128+128)
    float4 zca[4], zcb[4];
    #pragma unroll
    for (int c = 0; c < 4; ++c) {
        zca[c] = *(const float4*)(zr + c * 128 + gl * 8);
        zcb[c] = *(const float4*)(zr + c * 128 + gl * 8 + 4);
    }

    unsigned v = s1;
    #pragma unroll
    for (int m = 32; m; m >>= 1) v = umin32(v, (unsigned)__shfl_xor((int)v, m, 64));
    float thr = __uint_as_float(v & 0xFFFFFF80u) + MARGIN;
    float d1 = __uint_as_float(s1 & 0xFFFFFF80u);
    float d2 = __uint_as_float(s2 & 0xFFFFFF80u);
    bool full = d2 < thr;                             // lane == slice id
    ull fullMask = __ballot(full);
    ull singleMask = __ballot(!full && d1 < thr);

    float zn = znorm[t];
    ull lbest = ~0ull;                                // wave-uniform

    while (fullMask) {
        int bn = __builtin_ctzll(fullMask);
        fullMask &= fullMask - 1;
        int nb = bn * 128;
        for (int rep = 0; rep < 32; ++rep) {
            int n = nb + rep * 4 + grp;               // this group's candidate
            const float* cr = cb + (size_t)n * C_DIM + gl * 8;
            float4 ca0 = *(const float4*)(cr);
            float4 cb0 = *(const float4*)(cr + 4);
            float4 ca1 = *(const float4*)(cr + 128);
            float4 cb1 = *(const float4*)(cr + 132);
            float4 ca2 = *(const float4*)(cr + 256);
            float4 cb2 = *(const float4*)(cr + 260);
            float4 ca3 = *(const float4*)(cr + 384);
            float4 cb3 = *(const float4*)(cr + 388);
            float pA = dot8(zca[0], zcb[0], ca0, cb0);
            float pB = dot8(zca[1], zcb[1], ca1, cb1);
            float pC = dot8(zca[2], zcb[2], ca2, cb2);
            float pD = dot8(zca[3], zcb[3], ca3, cb3);
            float p = (pA + pB) + (pC + pD);
            #pragma unroll
            for (int m = 1; m <= 8; m <<= 1) p += __shfl_xor(p, m, 64);  // in-group
            float s = (zn - 2.0f * p) + enorm[n];
            ull pk = ((ull)__float_as_uint(s) << 32) | (unsigned)n;
            pk = umin64(pk, shfl_xor_u64(pk, 16));
            pk = umin64(pk, shfl_xor_u64(pk, 32));
            lbest = umin64(lbest, pk);
        }
    }
    while (singleMask) {
        // assign up to 4 single-candidates to the 4 groups
        ull m2 = singleMask;
        int myb = -1;
        #pragma unroll
        for (int j = 0; j < 4; ++j) {
            if (m2) {
                int b = __builtin_ctzll(m2);
                m2 &= m2 - 1;
                if (j == grp) myb = b;
            }
        }
        singleMask = m2;
        int bsrc = (myb >= 0) ? myb : 0;
        int scode = __shfl((int)s1, bsrc, 64) & 0x7F;   // bpermute, any src lane
        ull pk = ~0ull;
        if (myb >= 0) {
            int n = myb * 128 + scode;
            const float* cr = cb + (size_t)n * C_DIM + gl * 8;
            float4 ca0 = *(const float4*)(cr);
            float4 cb0 = *(const float4*)(cr + 4);
            float4 ca1 = *(const float4*)(cr + 128);
            float4 cb1 = *(const float4*)(cr + 132);
            float4 ca2 = *(const float4*)(cr + 256);
            float4 cb2 = *(const float4*)(cr + 260);
            float4 ca3 = *(const float4*)(cr + 384);
            float4 cb3 = *(const float4*)(cr + 388);
            float pA = dot8(zca[0], zcb[0], ca0, cb0);
            float pB = dot8(zca[1], zcb[1], ca1, cb1);
            float pC = dot8(zca[2], zcb[2], ca2, cb2);
            float pD = dot8(zca[3], zcb[3], ca3, cb3);
            float p = (pA + pB) + (pC + pD);
            #pragma unroll
            for (int m = 1; m <= 8; m <<= 1) p += __shfl_xor(p, m, 64);  // in-group
            float s = (zn - 2.0f * p) + enorm[n];
            pk = ((ull)__float_as_uint(s) << 32) | (unsigned)n;
        }
        pk = umin64(pk, shfl_xor_u64(pk, 16));
        pk = umin64(pk, shfl_xor_u64(pk, 32));
        lbest = umin64(lbest, pk);
    }
    int idx = (int)(unsigned)(lbest & 0xFFFFFFFFull);

    // fused gather: whole wave holds the token's z row
    const float* qr = cb + (size_t)idx * C_DIM + lane * 8;
    float4 q0 = *(const float4*)qr;
    float4 q1 = *(const float4*)(qr + 4);
    float4 o0, o1;
    o0.x = z0.x + (q0.x - z0.x); o0.y = z0.y + (q0.y - z0.y);
    o0.z = z0.z + (q0.z - z0.z); o0.w = z0.w + (q0.w - z0.w);
    o1.x = z1.x + (q1.x - z1.x); o1.y = z1.y + (q1.y - z1.y);
    o1.z = z1.z + (q1.z - z1.z); o1.w = z1.w + (q1.w - z1.w);
    float* zq = out + ZQ_OFF + (size_t)t * C_DIM + lane * 8;
    *(float4*)zq = o0;
    *(float4*)(zq + 4) = o1;
    float d, l = 0.0f;
    d = z0.x - q0.x; l = fmaf(d, d, l);
    d = z0.y - q0.y; l = fmaf(d, d, l);
    d = z0.z - q0.z; l = fmaf(d, d, l);
    d = z0.w - q0.w; l = fmaf(d, d, l);
    d = z1.x - q1.x; l = fmaf(d, d, l);
    d = z1.y - q1.y; l = fmaf(d, d, l);
    d = z1.z - q1.z; l = fmaf(d, d, l);
    d = z1.w - q1.w; l = fmaf(d, d, l);
    #pragma unroll
    for (int m = 32; m; m >>= 1) l += __shfl_down(l, m, 64);
    if (lane == 0) {
        lossP[t] = l * (BETA / ((float)T_TOK * (float)C_DIM));  // plain store
        out[IDX_OFF + t] = (float)idx;
        atomicAdd(&icount[idx], 1);
    }
}

// ---- K4: fused scan + ncs + nsum + loss + scatter (single block) ------------
__global__ __launch_bounds__(256) void scan_ncs_scatter_kernel(
        const int* __restrict__ icount, const float* __restrict__ cs,
        const float* __restrict__ lossP, const float* __restrict__ outIdx,
        int* __restrict__ offsB, int* __restrict__ list,
        float* __restrict__ out, float* __restrict__ nsum) {
    __shared__ int tot[256];
    __shared__ int ofs[8192];                 // 32 KB slot counters
    int tid = threadIdx.x;
    float ncsSum = 0.0f, lsum = 0.0f;
    // pass 1: coalesced — ncs compute+store, sums, L1-warm icount
    #pragma unroll
    for (int j = 0; j < 32; ++j) {
        int k = j * 256 + tid;                // coalesced
        int x = icount[k];
        float ncs = cs[k] * DECAY + (float)x * ONE_MINUS_DECAY;
        out[NCS_OFF + k] = ncs;               // coalesced
        ncsSum += ncs;
        lsum += lossP[k];                     // coalesced
    }
    // pass 2: per-thread serial prefix over contiguous chunk (icount L1-hot)
    int v[32];
    int s = 0;
    #pragma unroll
    for (int j = 0; j < 32; ++j) {
        int x = icount[tid * 32 + j];
        v[j] = s;
        s += x;
    }
    tot[tid] = s;
    __syncthreads();
    for (int d = 1; d < 256; d <<= 1) {
        int x = (tid >= d) ? tot[tid - d] : 0;
        __syncthreads();
        tot[tid] += x;
        __syncthreads();
    }
    int excl = tid ? tot[tid - 1] : 0;
    #pragma unroll
    for (int j = 0; j < 32; ++j) {
        ofs[tid * 32 + j] = excl + v[j];
    }
    __syncthreads();
    // offsB written coalesced from LDS
    #pragma unroll
    for (int j = 0; j < 32; ++j) {
        int k = j * 256 + tid;
        offsB[k] = ofs[k];
    }
    // scatter all 8192 tokens (coalesced idx reads, LDS-atomic slots)
    for (int base = 0; base < T_TOK; base += 256) {
        int t = base + tid;
        int idx = (int)outIdx[t];
        int slot = atomicAdd(&ofs[idx], 1);
        list[slot] = t;
    }
    // block-wide float reductions for nsum and loss
    float a = ncsSum, l = lsum;
    #pragma unroll
    for (int m = 32; m; m >>= 1) { a += __shfl_down(a, m, 64); l += __shfl_down(l, m, 64); }
    __shared__ float redA[4], redL[4];
    if ((tid & 63) == 0) { redA[tid >> 6] = a; redL[tid >> 6] = l; }
    __syncthreads();
    if (tid == 0) {
        nsum[0] = (redA[0] + redA[1]) + (redA[2] + redA[3]);
        out[LOSS_OFF] = (redL[0] + redL[1]) + (redL[2] + redL[3]);
    }
}

// ---- K5a (ws path): MERGED per-code segment sum + finalize ------------------
__global__ __launch_bounds__(256) void percode_finalize_kernel(
        const float* __restrict__ z, const float* __restrict__ ea,
        const int* __restrict__ list, const int* __restrict__ offsB,
        const int* __restrict__ icount, float* __restrict__ out,
        const float* __restrict__ nsumP) {
    int k = blockIdx.x;
    int tid = threadIdx.x;
    int off = offsB[k], cnt = icount[k];
    float a0 = 0.0f, a1 = 0.0f;
    for (int i = 0; i < cnt; ++i) {
        int t = list[off + i];
        const float* zrow = z + (size_t)t * C_DIM;
        a0 += zrow[tid];
        a1 += zrow[tid + 256];
    }
    float n = fmaxf(*nsumP, 1.0f);
    float ncs = out[NCS_OFF + k];
    float smoothed = ((ncs + EPS_F) / (n + K_EPS)) * n;
    size_t o0 = (size_t)k * C_DIM + tid;
    size_t o1 = o0 + 256;
    float nea0 = ea[o0] * DECAY + a0 * ONE_MINUS_DECAY;
    float nea1 = ea[o1] * DECAY + a1 * ONE_MINUS_DECAY;
    out[NEA_OFF + o0] = nea0;
    out[NEA_OFF + o1] = nea1;
    out[NCB_OFF + o0] = nea0 / smoothed;
    out[NCB_OFF + o1] = nea1 / smoothed;
}

// ---- K5b/K6b (fallback, list in out): split pair ----------------------------
__global__ __launch_bounds__(256) void percode_sum_kernel(
        const float* __restrict__ z, const int* __restrict__ list,
        const int* __restrict__ offsB, const int* __restrict__ icount,
        float* __restrict__ out) {
    int k = blockIdx.x;
    int tid = threadIdx.x;
    int off = offsB[k], cnt = icount[k];
    float a0 = 0.0f, a1 = 0.0f;
    for (int i = 0; i < cnt; ++i) {
        int t = list[off + i];
        const float* zrow = z + (size_t)t * C_DIM;
        a0 += zrow[tid];
        a1 += zrow[tid + 256];
    }
    out[NCB_OFF + (size_t)k * C_DIM + tid] = a0;
    out[NCB_OFF + (size_t)k * C_DIM + tid + 256] = a1;
}

__global__ __launch_bounds__(256) void finalize_kernel(const float* __restrict__ ea,
                                                       float* __restrict__ out,
                                                       const float* __restrict__ nsumP) {
    int k = blockIdx.x;
    int tid = threadIdx.x;
    float n = fmaxf(*nsumP, 1.0f);
    float ncs = out[NCS_OFF + k];
    float smoothed = ((ncs + EPS_F) / (n + K_EPS)) * n;
    #pragma unroll
    for (int s = 0; s < 2; ++s) {
        int c = tid + s * 256;
        size_t o = (size_t)k * C_DIM + c;
        float es = out[NCB_OFF + o];                       // staged embed_sum
        float nea = ea[o] * DECAY + es * ONE_MINUS_DECAY;
        out[NEA_OFF + o] = nea;
        out[NCB_OFF + o] = nea / smoothed;
    }
}

extern "C" void kernel_launch(void* const* d_in, const int* in_sizes, int n_in,
                              void* d_out, int out_size, void* d_ws, size_t ws_size,
                              hipStream_t stream) {
    const float* z  = (const float*)d_in[0];
    const float* cb = (const float*)d_in[1];
    const float* cs = (const float*)d_in[2];
    const float* ea = (const float*)d_in[3];
    float* out = (float*)d_out;
    float* ws  = (float*)d_ws;
    _Float16* zp = (_Float16*)out;
    _Float16* cp = (_Float16*)(out + CP_F_OFF);
    float* lossP = out + LOSSP_F_OFF;              // dead gap after slab2
    unsigned* slab1 = (unsigned*)(out + SLAB1_F_OFF);
    unsigned* slab2 = (unsigned*)(out + SLAB2_F_OFF);
    int* icount = (int*)(ws + WS_ICOUNT);
    float* nsum = ws + WS_NSUM;

    bool wsbig = ws_size >= WS_NEED_BYTES;
    int* list  = wsbig ? (int*)(ws + WS_LIST)  : (int*)(out + LIST_I_OFF);
    int* offsB = wsbig ? (int*)(ws + WS_OFFSB) : (int*)(out + OFFSB_I_OFF);

    prep_kernel<<<8192, 256, 0, stream>>>(z, cb, zp, cp, ws, icount);
    dist_mfma_kernel<<<4096, 256, 0, stream>>>(zp, cp, ws + WS_ZNORM, ws + WS_ENORM, slab1, slab2);
    refine_gather_kernel<<<2048, 256, 0, stream>>>(z, cb, ws + WS_ZNORM, ws + WS_ENORM,
                                                   slab1, slab2, out, icount, lossP);
    scan_ncs_scatter_kernel<<<1, 256, 0, stream>>>(icount, cs, lossP, out + IDX_OFF,
                                                   offsB, list, out, nsum);
    if (wsbig) {
        percode_finalize_kernel<<<8192, 256, 0, stream>>>(z, ea, list, offsB, icount, out, nsum);
    } else {
        percode_sum_kernel<<<8192, 256, 0, stream>>>(z, list, offsB, icount, out);
        finalize_kernel<<<8192, 256, 0, stream>>>(ea, out, nsum);
    }
}

// Round 14
// 261.467 us; speedup vs baseline: 1.0352x; 1.0352x over previous
//
#include <hip/hip_runtime.h>
#include <cstdint>
#include <cstddef>

// Problem constants
#define T_TOK 8192
#define K_CODE 8192
#define C_DIM 512
#define BETA 0.25f
#define DECAY 0.99f
#define ONE_MINUS_DECAY 0.01f
#define EPS_F 1e-5f
#define K_EPS 0.08192f
// Coarse-dist error: f16 GEMM bound 0.025 + key quantization 2*0.002;
// sufficiency needs MARGIN > 2*(E1+eq) = 0.054 -> 0.0625 still conservative.
#define MARGIN 0.0625f

// d_out layout (floats, concatenated in reference return order)
#define ZQ_OFF   ((size_t)0)          // z_q_st      [8,1024,512] = 4194304
#define IDX_OFF  ((size_t)4194304)    // indices     [8,1024]     = 8192
#define LOSS_OFF ((size_t)4202496)    // vq_loss     scalar       = 1
#define NCB_OFF  ((size_t)4202497)    // new_codebook[8192,512]   = 4194304
#define NCS_OFF  ((size_t)8396801)    // new_cluster [8192]       = 8192
#define NEA_OFF  ((size_t)8404993)    // new_embed_avg[8192,512]  = 4194304

// Transient regions (all stream-ordered, lifetime-checked):
//   zp f16 = floats [0, 2097152); cp f16 = floats [2097152, 4194304) —
//     both dead after dist (refine then writes ZQ over them).
//   slab1/slab2 u32[8192*64] each at [8404994, 9453570) — transposed [t][bn];
//     written by dist, read by refine, dead before NEA writes.
//   lossP f32[8192] at [9453570, 9461762) — written by refine (plain stores;
//     MUST stay outside ZQ — round-6 race), read by scan_ncs_scatter, dead
//     before NEA writes.
//   list/offsB: in d_ws when ws_size permits (enables merged
//     percode_finalize, which writes NEA without racing them); else in out
//     after lossP (fallback: percode/finalize stay SPLIT because finalize's
//     NEA write would clobber live list rows ~4096-4127).
#define CP_F_OFF    ((size_t)2097152)
#define SLAB1_F_OFF ((size_t)8404994)
#define SLAB2_F_OFF ((size_t)(8404994 + 524288))
#define LOSSP_F_OFF ((size_t)9453570)
#define LIST_I_OFF  ((size_t)10502146)
#define OFFSB_I_OFF ((size_t)10518530)

// d_ws layout (float offsets)
#define WS_ZNORM  0
#define WS_ENORM  8192
#define WS_ICOUNT 16384   // int[8192]
#define WS_NSUM   24576
#define WS_LIST   24608   // int[8192]  (only if ws_size >= 163968 B)
#define WS_OFFSB  32800   // int[8192]
#define WS_NEED_BYTES ((size_t)(32800 + 8192) * 4)

typedef _Float16 half8 __attribute__((ext_vector_type(8)));
typedef _Float16 half4v __attribute__((ext_vector_type(4)));
typedef float floatx4 __attribute__((ext_vector_type(4)));
typedef unsigned long long ull;

__device__ __forceinline__ void gload16(const void* g, void* l) {
    __builtin_amdgcn_global_load_lds(
        (const __attribute__((address_space(1))) void*)g,
        (__attribute__((address_space(3))) void*)l, 16, 0, 0);
}

__device__ __forceinline__ unsigned umin32(unsigned a, unsigned b) { return a < b ? a : b; }
__device__ __forceinline__ unsigned umax32(unsigned a, unsigned b) { return a > b ? a : b; }
__device__ __forceinline__ ull umin64(ull a, ull b) { return a < b ? a : b; }

__device__ inline ull shfl_xor_u64(ull v, int m) {
    int lo = (int)(unsigned)(v & 0xFFFFFFFFull);
    int hi = (int)(unsigned)(v >> 32);
    lo = __shfl_xor(lo, m, 64);
    hi = __shfl_xor(hi, m, 64);
    return ((ull)(unsigned)hi << 32) | (unsigned)lo;
}

__device__ __forceinline__ float dot8(float4 z0, float4 z1, float4 c0, float4 c1) {
    float p = 0.0f;
    p = fmaf(z0.x, c0.x, p); p = fmaf(z0.y, c0.y, p);
    p = fmaf(z0.z, c0.z, p); p = fmaf(z0.w, c0.w, p);
    p = fmaf(z1.x, c1.x, p); p = fmaf(z1.y, c1.y, p);
    p = fmaf(z1.z, c1.z, p); p = fmaf(z1.w, c1.w, p);
    return p;
}

// ---- K1: f16 convert pack + row norms + icount zeroing ----------------------
__global__ __launch_bounds__(256) void prep_kernel(const float* __restrict__ z,
                                                   const float* __restrict__ cb,
                                                   _Float16* __restrict__ zp,
                                                   _Float16* __restrict__ cp,
                                                   float* __restrict__ ws,
                                                   int* __restrict__ icount) {
    int tid = threadIdx.x;
    if (blockIdx.x < 32) icount[blockIdx.x * 256 + tid] = 0;  // replaces memset launch
    int row = blockIdx.x * 2 + (tid >> 7);   // 0..16383
    int l128 = tid & 127;
    const float* src;
    _Float16* dst;
    float* nrm;
    if (row < T_TOK) { src = z + (size_t)row * C_DIM; dst = zp + (size_t)row * C_DIM; nrm = ws + WS_ZNORM + row; }
    else { int r = row - T_TOK; src = cb + (size_t)r * C_DIM; dst = cp + (size_t)r * C_DIM; nrm = ws + WS_ENORM + r; }
    float4 v = *(const float4*)(src + l128 * 4);
    half4v h;
    h[0] = (_Float16)v.x; h[1] = (_Float16)v.y;
    h[2] = (_Float16)v.z; h[3] = (_Float16)v.w;
    *(half4v*)(dst + l128 * 4) = h;          // 8 B packed store
    float s = v.x * v.x + v.y * v.y + v.z * v.z + v.w * v.w;
    #pragma unroll
    for (int m = 32; m; m >>= 1) s += __shfl_down(s, m, 64);
    __shared__ float red[4];
    if ((tid & 63) == 0) red[tid >> 6] = s;
    __syncthreads();
    if ((tid & 127) == 0) nrm[0] = red[tid >> 6] + red[(tid >> 6) + 1];
}

// ---- K2: coarse f16 MFMA GEMM (K=512) + per-slice top-2 slab ----------------
// FINAL FORM (119.7 µs verified, rounds 10/12). 128x128 tile, single-buffer
// BK=32 2-barrier loop, u32 packed keys, transposed slab writes, XCD-bijective
// swizzle (FETCH ~25 MB). Restructure scoreboard (all regressed): explicit
// dbuf 160, BK=64 181, BM=64 133, __launch_bounds__(256,4) 126 (spill:
// WRITE 20->99 MB; and at 40% occupancy MfmaUtil did NOT rise — occupancy is
// not the limiter; the barrier-synced vmcnt(0) drain is). Next lever beyond
// this floor is the 256²/8-phase counted-vmcnt template (full rewrite).
__global__ __launch_bounds__(256) void dist_mfma_kernel(
        const _Float16* __restrict__ zp, const _Float16* __restrict__ cp,
        const float* __restrict__ znorm, const float* __restrict__ enorm,
        unsigned* __restrict__ slab1, unsigned* __restrict__ slab2) {
    __shared__ __align__(16) _Float16 As[128 * 32];
    __shared__ __align__(16) _Float16 Bs[128 * 32];
    __shared__ unsigned red2[128][2][2];
    const int tid = threadIdx.x;
    const int w = tid >> 6, lane = tid & 63;
    const int quad = lane >> 4, lr = lane & 15;
    const int wm = w >> 1, wn = w & 1;

    const int GRID_N = 64, GROUP_M = 16;
    int pid0 = blockIdx.x;
    int pid = (pid0 & 7) * 512 + (pid0 >> 3);   // XCD swizzle: 4096/8 = 512
    int per = GROUP_M * GRID_N;
    int g = pid / per;
    int local = pid % per;
    int bm = g * GROUP_M + (local & (GROUP_M - 1));
    int bn = local / GROUP_M;
    const int mBase = bm * 128, nBase = bn * 128;

    int r0 = (w * 2 + 0) * 16 + (lane >> 2);
    int r1 = (w * 2 + 1) * 16 + (lane >> 2);
    int cq = (((lane & 3) ^ ((lane >> 3) & 3))) * 8;
    const _Float16* ga0 = zp + (size_t)(mBase + r0) * C_DIM + cq;
    const _Float16* ga1 = zp + (size_t)(mBase + r1) * C_DIM + cq;
    const _Float16* gb0 = cp + (size_t)(nBase + r0) * C_DIM + cq;
    const _Float16* gb1 = cp + (size_t)(nBase + r1) * C_DIM + cq;
    _Float16* la0 = As + (w * 2 + 0) * 512;
    _Float16* la1 = As + (w * 2 + 1) * 512;
    _Float16* lb0 = Bs + (w * 2 + 0) * 512;
    _Float16* lb1 = Bs + (w * 2 + 1) * 512;

    const int slotA = (quad ^ ((lr >> 1) & 3)) * 8;
    const _Float16* aFrag = As + ((size_t)(wm * 64 + lr)) * 32 + slotA;
    const _Float16* bFrag = Bs + ((size_t)(wn * 64 + lr)) * 32 + slotA;

    floatx4 acc[4][4] = {};

    for (int it = 0; it < 16; ++it) {
        __syncthreads();
        gload16(ga0, la0);
        gload16(ga1, la1);
        gload16(gb0, lb0);
        gload16(gb1, lb1);
        ga0 += 32; ga1 += 32; gb0 += 32; gb1 += 32;
        __syncthreads();
        half8 af[4], bf[4];
        #pragma unroll
        for (int i = 0; i < 4; ++i) af[i] = *(const half8*)(aFrag + i * 16 * 32);
        #pragma unroll
        for (int j = 0; j < 4; ++j) bf[j] = *(const half8*)(bFrag + j * 16 * 32);
        #pragma unroll
        for (int i = 0; i < 4; ++i)
            #pragma unroll
            for (int j = 0; j < 4; ++j)
                acc[i][j] = __builtin_amdgcn_mfma_f32_16x16x32_f16(af[i], bf[j], acc[i][j], 0, 0, 0);
    }

    float en[4];
    #pragma unroll
    for (int j = 0; j < 4; ++j) en[j] = enorm[nBase + wn * 64 + j * 16 + lr];
    #pragma unroll
    for (int i = 0; i < 4; ++i) {
        #pragma unroll
        for (int r = 0; r < 4; ++r) {
            int lrow = wm * 64 + i * 16 + quad * 4 + r;
            float zn = znorm[mBase + lrow];
            unsigned t1 = 0xFFFFFFFFu, t2 = 0xFFFFFFFFu;
            #pragma unroll
            for (int j = 0; j < 4; ++j) {
                int nLoc = wn * 64 + j * 16 + lr;            // 0..127 within slice
                float s = (zn - 2.0f * acc[i][j][r]) + en[j];
                s = fmaxf(s, 0.0f);                          // keep uint ordering valid
                unsigned key = ((__float_as_uint(s) + 0x40u) & 0xFFFFFF80u) | (unsigned)nLoc;
                if (key < t1) { t2 = t1; t1 = key; } else if (key < t2) t2 = key;
            }
            #pragma unroll
            for (int msk = 1; msk < 16; msk <<= 1) {
                unsigned o1 = (unsigned)__shfl_xor((int)t1, msk, 64);
                unsigned o2 = (unsigned)__shfl_xor((int)t2, msk, 64);
                unsigned n1 = umin32(t1, o1);
                unsigned n2 = umin32(umax32(t1, o1), umin32(t2, o2));
                t1 = n1; t2 = n2;
            }
            if (lr == 0) { red2[lrow][wn][0] = t1; red2[lrow][wn][1] = t2; }
        }
    }
    __syncthreads();
    if (tid < 128) {
        unsigned a1 = red2[tid][0][0], a2 = red2[tid][0][1];
        unsigned b1 = red2[tid][1][0], b2 = red2[tid][1][1];
        unsigned m1 = umin32(a1, b1);
        unsigned m2 = umin32(umax32(a1, b1), umin32(a2, b2));
        slab1[(size_t)(mBase + tid) * 64 + bn] = m1;   // transposed [t][bn]
        slab2[(size_t)(mBase + tid) * 64 + bn] = m2;
    }
}

// ---- K3: refine + fused gather --------------------------------------------
// One WAVE per token; 16-lane-GROUP dot products (each group owns one
// candidate; z chunked per-lane). UNCHANGED (verified round 10/12).
__global__ __launch_bounds__(256) void refine_gather_kernel(
        const float* __restrict__ z, const float* __restrict__ cb,
        const float* __restrict__ znorm, const float* __restrict__ enorm,
        const unsigned* __restrict__ slab1, const unsigned* __restrict__ slab2,
        float* __restrict__ out, int* __restrict__ icount,
        float* __restrict__ lossP) {
    int tid = threadIdx.x;
    int wv = tid >> 6, lane = tid & 63;
    int grp = lane >> 4, gl = lane & 15;
    int t = blockIdx.x * 4 + wv;

    unsigned s1 = slab1[(size_t)t * 64 + lane];      // coalesced: 64 x u32
    unsigned s2 = slab2[(size_t)t * 64 + lane];
    const float* zr = z + (size_t)t * C_DIM;
    float4 z0 = *(const float4*)(zr + lane * 8);
    float4 z1 = *(const float4*)(zr + lane * 8 + 4);
    // chunked z copy for group dots: chunk c covers cols [c*128, c*128+128)
    float4 zca[4], zcb[4];
    #pragma unroll
    for (int c = 0; c < 4; ++c) {
        zca[c] = *(const float4*)(zr + c * 128 + gl * 8);
        zcb[c] = *(const float4*)(zr + c * 128 + gl * 8 + 4);
    }

    unsigned v = s1;
    #pragma unroll
    for (int m = 32; m; m >>= 1) v = umin32(v, (unsigned)__shfl_xor((int)v, m, 64));
    float thr = __uint_as_float(v & 0xFFFFFF80u) + MARGIN;
    float d1 = __uint_as_float(s1 & 0xFFFFFF80u);
    float d2 = __uint_as_float(s2 & 0xFFFFFF80u);
    bool full = d2 < thr;                             // lane == slice id
    ull fullMask = __ballot(full);
    ull singleMask = __ballot(!full && d1 < thr);

    float zn = znorm[t];
    ull lbest = ~0ull;                                // wave-uniform

    while (fullMask) {
        int bn = __builtin_ctzll(fullMask);
        fullMask &= fullMask - 1;
        int nb = bn * 128;
        for (int rep = 0; rep < 32; ++rep) {
            int n = nb + rep * 4 + grp;               // this group's candidate
            const float* cr = cb + (size_t)n * C_DIM + gl * 8;
            float4 ca0 = *(const float4*)(cr);
            float4 cb0 = *(const float4*)(cr + 4);
            float4 ca1 = *(const float4*)(cr + 128);
            float4 cb1 = *(const float4*)(cr + 132);
            float4 ca2 = *(const float4*)(cr + 256);
            float4 cb2 = *(const float4*)(cr + 260);
            float4 ca3 = *(const float4*)(cr + 384);
            float4 cb3 = *(const float4*)(cr + 388);
            float pA = dot8(zca[0], zcb[0], ca0, cb0);
            float pB = dot8(zca[1], zcb[1], ca1, cb1);
            float pC = dot8(zca[2], zcb[2], ca2, cb2);
            float pD = dot8(zca[3], zcb[3], ca3, cb3);
            float p = (pA + pB) + (pC + pD);
            #pragma unroll
            for (int m = 1; m <= 8; m <<= 1) p += __shfl_xor(p, m, 64);  // in-group
            float s = (zn - 2.0f * p) + enorm[n];
            ull pk = ((ull)__float_as_uint(s) << 32) | (unsigned)n;
            pk = umin64(pk, shfl_xor_u64(pk, 16));
            pk = umin64(pk, shfl_xor_u64(pk, 32));
            lbest = umin64(lbest, pk);
        }
    }
    while (singleMask) {
        // assign up to 4 single-candidates to the 4 groups
        ull m2 = singleMask;
        int myb = -1;
        #pragma unroll
        for (int j = 0; j < 4; ++j) {
            if (m2) {
                int b = __builtin_ctzll(m2);
                m2 &= m2 - 1;
                if (j == grp) myb = b;
            }
        }
        singleMask = m2;
        int bsrc = (myb >= 0) ? myb : 0;
        int scode = __shfl((int)s1, bsrc, 64) & 0x7F;   // bpermute, any src lane
        ull pk = ~0ull;
        if (myb >= 0) {
            int n = myb * 128 + scode;
            const float* cr = cb + (size_t)n * C_DIM + gl * 8;
            float4 ca0 = *(const float4*)(cr);
            float4 cb0 = *(const float4*)(cr + 4);
            float4 ca1 = *(const float4*)(cr + 128);
            float4 cb1 = *(const float4*)(cr + 132);
            float4 ca2 = *(const float4*)(cr + 256);
            float4 cb2 = *(const float4*)(cr + 260);
            float4 ca3 = *(const float4*)(cr + 384);
            float4 cb3 = *(const float4*)(cr + 388);
            float pA = dot8(zca[0], zcb[0], ca0, cb0);
            float pB = dot8(zca[1], zcb[1], ca1, cb1);
            float pC = dot8(zca[2], zcb[2], ca2, cb2);
            float pD = dot8(zca[3], zcb[3], ca3, cb3);
            float p = (pA + pB) + (pC + pD);
            #pragma unroll
            for (int m = 1; m <= 8; m <<= 1) p += __shfl_xor(p, m, 64);  // in-group
            float s = (zn - 2.0f * p) + enorm[n];
            pk = ((ull)__float_as_uint(s) << 32) | (unsigned)n;
        }
        pk = umin64(pk, shfl_xor_u64(pk, 16));
        pk = umin64(pk, shfl_xor_u64(pk, 32));
        lbest = umin64(lbest, pk);
    }
    int idx = (int)(unsigned)(lbest & 0xFFFFFFFFull);

    // fused gather: whole wave holds the token's z row
    const float* qr = cb + (size_t)idx * C_DIM + lane * 8;
    float4 q0 = *(const float4*)qr;
    float4 q1 = *(const float4*)(qr + 4);
    float4 o0, o1;
    o0.x = z0.x + (q0.x - z0.x); o0.y = z0.y + (q0.y - z0.y);
    o0.z = z0.z + (q0.z - z0.z); o0.w = z0.w + (q0.w - z0.w);
    o1.x = z1.x + (q1.x - z1.x); o1.y = z1.y + (q1.y - z1.y);
    o1.z = z1.z + (q1.z - z1.z); o1.w = z1.w + (q1.w - z1.w);
    float* zq = out + ZQ_OFF + (size_t)t * C_DIM + lane * 8;
    *(float4*)zq = o0;
    *(float4*)(zq + 4) = o1;
    float d, l = 0.0f;
    d = z0.x - q0.x; l = fmaf(d, d, l);
    d = z0.y - q0.y; l = fmaf(d, d, l);
    d = z0.z - q0.z; l = fmaf(d, d, l);
    d = z0.w - q0.w; l = fmaf(d, d, l);
    d = z1.x - q1.x; l = fmaf(d, d, l);
    d = z1.y - q1.y; l = fmaf(d, d, l);
    d = z1.z - q1.z; l = fmaf(d, d, l);
    d = z1.w - q1.w; l = fmaf(d, d, l);
    #pragma unroll
    for (int m = 32; m; m >>= 1) l += __shfl_down(l, m, 64);
    if (lane == 0) {
        lossP[t] = l * (BETA / ((float)T_TOK * (float)C_DIM));  // plain store
        out[IDX_OFF + t] = (float)idx;
        atomicAdd(&icount[idx], 1);
    }
}

// ---- K4: fused scan + ncs + nsum + loss + scatter (single block) ------------
__global__ __launch_bounds__(256) void scan_ncs_scatter_kernel(
        const int* __restrict__ icount, const float* __restrict__ cs,
        const float* __restrict__ lossP, const float* __restrict__ outIdx,
        int* __restrict__ offsB, int* __restrict__ list,
        float* __restrict__ out, float* __restrict__ nsum) {
    __shared__ int tot[256];
    __shared__ int ofs[8192];                 // 32 KB slot counters
    int tid = threadIdx.x;
    float ncsSum = 0.0f, lsum = 0.0f;
    // pass 1: coalesced — ncs compute+store, sums, L1-warm icount
    #pragma unroll
    for (int j = 0; j < 32; ++j) {
        int k = j * 256 + tid;                // coalesced
        int x = icount[k];
        float ncs = cs[k] * DECAY + (float)x * ONE_MINUS_DECAY;
        out[NCS_OFF + k] = ncs;               // coalesced
        ncsSum += ncs;
        lsum += lossP[k];                     // coalesced
    }
    // pass 2: per-thread serial prefix over contiguous chunk (icount L1-hot)
    int v[32];
    int s = 0;
    #pragma unroll
    for (int j = 0; j < 32; ++j) {
        int x = icount[tid * 32 + j];
        v[j] = s;
        s += x;
    }
    tot[tid] = s;
    __syncthreads();
    for (int d = 1; d < 256; d <<= 1) {
        int x = (tid >= d) ? tot[tid - d] : 0;
        __syncthreads();
        tot[tid] += x;
        __syncthreads();
    }
    int excl = tid ? tot[tid - 1] : 0;
    #pragma unroll
    for (int j = 0; j < 32; ++j) {
        ofs[tid * 32 + j] = excl + v[j];
    }
    __syncthreads();
    // offsB written coalesced from LDS
    #pragma unroll
    for (int j = 0; j < 32; ++j) {
        int k = j * 256 + tid;
        offsB[k] = ofs[k];
    }
    // scatter all 8192 tokens (coalesced idx reads, LDS-atomic slots)
    for (int base = 0; base < T_TOK; base += 256) {
        int t = base + tid;
        int idx = (int)outIdx[t];
        int slot = atomicAdd(&ofs[idx], 1);
        list[slot] = t;
    }
    // block-wide float reductions for nsum and loss
    float a = ncsSum, l = lsum;
    #pragma unroll
    for (int m = 32; m; m >>= 1) { a += __shfl_down(a, m, 64); l += __shfl_down(l, m, 64); }
    __shared__ float redA[4], redL[4];
    if ((tid & 63) == 0) { redA[tid >> 6] = a; redL[tid >> 6] = l; }
    __syncthreads();
    if (tid == 0) {
        nsum[0] = (redA[0] + redA[1]) + (redA[2] + redA[3]);
        out[LOSS_OFF] = (redL[0] + redL[1]) + (redL[2] + redL[3]);
    }
}

// ---- K5a (ws path): MERGED per-code segment sum + finalize ------------------
__global__ __launch_bounds__(256) void percode_finalize_kernel(
        const float* __restrict__ z, const float* __restrict__ ea,
        const int* __restrict__ list, const int* __restrict__ offsB,
        const int* __restrict__ icount, float* __restrict__ out,
        const float* __restrict__ nsumP) {
    int k = blockIdx.x;
    int tid = threadIdx.x;
    int off = offsB[k], cnt = icount[k];
    float a0 = 0.0f, a1 = 0.0f;
    for (int i = 0; i < cnt; ++i) {
        int t = list[off + i];
        const float* zrow = z + (size_t)t * C_DIM;
        a0 += zrow[tid];
        a1 += zrow[tid + 256];
    }
    float n = fmaxf(*nsumP, 1.0f);
    float ncs = out[NCS_OFF + k];
    float smoothed = ((ncs + EPS_F) / (n + K_EPS)) * n;
    size_t o0 = (size_t)k * C_DIM + tid;
    size_t o1 = o0 + 256;
    float nea0 = ea[o0] * DECAY + a0 * ONE_MINUS_DECAY;
    float nea1 = ea[o1] * DECAY + a1 * ONE_MINUS_DECAY;
    out[NEA_OFF + o0] = nea0;
    out[NEA_OFF + o1] = nea1;
    out[NCB_OFF + o0] = nea0 / smoothed;
    out[NCB_OFF + o1] = nea1 / smoothed;
}

// ---- K5b/K6b (fallback, list in out): split pair ----------------------------
__global__ __launch_bounds__(256) void percode_sum_kernel(
        const float* __restrict__ z, const int* __restrict__ list,
        const int* __restrict__ offsB, const int* __restrict__ icount,
        float* __restrict__ out) {
    int k = blockIdx.x;
    int tid = threadIdx.x;
    int off = offsB[k], cnt = icount[k];
    float a0 = 0.0f, a1 = 0.0f;
    for (int i = 0; i < cnt; ++i) {
        int t = list[off + i];
        const float* zrow = z + (size_t)t * C_DIM;
        a0 += zrow[tid];
        a1 += zrow[tid + 256];
    }
    out[NCB_OFF + (size_t)k * C_DIM + tid] = a0;
    out[NCB_OFF + (size_t)k * C_DIM + tid + 256] = a1;
}

__global__ __launch_bounds__(256) void finalize_kernel(const float* __restrict__ ea,
                                                       float* __restrict__ out,
                                                       const float* __restrict__ nsumP) {
    int k = blockIdx.x;
    int tid = threadIdx.x;
    float n = fmaxf(*nsumP, 1.0f);
    float ncs = out[NCS_OFF + k];
    float smoothed = ((ncs + EPS_F) / (n + K_EPS)) * n;
    #pragma unroll
    for (int s = 0; s < 2; ++s) {
        int c = tid + s * 256;
        size_t o = (size_t)k * C_DIM + c;
        float es = out[NCB_OFF + o];                       // staged embed_sum
        float nea = ea[o] * DECAY + es * ONE_MINUS_DECAY;
        out[NEA_OFF + o] = nea;
        out[NCB_OFF + o] = nea / smoothed;
    }
}

extern "C" void kernel_launch(void* const* d_in, const int* in_sizes, int n_in,
                              void* d_out, int out_size, void* d_ws, size_t ws_size,
                              hipStream_t stream) {
    const float* z  = (const float*)d_in[0];
    const float* cb = (const float*)d_in[1];
    const float* cs = (const float*)d_in[2];
    const float* ea = (const float*)d_in[3];
    float* out = (float*)d_out;
    float* ws  = (float*)d_ws;
    _Float16* zp = (_Float16*)out;
    _Float16* cp = (_Float16*)(out + CP_F_OFF);
    float* lossP = out + LOSSP_F_OFF;              // dead gap after slab2
    unsigned* slab1 = (unsigned*)(out + SLAB1_F_OFF);
    unsigned* slab2 = (unsigned*)(out + SLAB2_F_OFF);
    int* icount = (int*)(ws + WS_ICOUNT);
    float* nsum = ws + WS_NSUM;

    bool wsbig = ws_size >= WS_NEED_BYTES;
    int* list  = wsbig ? (int*)(ws + WS_LIST)  : (int*)(out + LIST_I_OFF);
    int* offsB = wsbig ? (int*)(ws + WS_OFFSB) : (int*)(out + OFFSB_I_OFF);

    prep_kernel<<<8192, 256, 0, stream>>>(z, cb, zp, cp, ws, icount);
    dist_mfma_kernel<<<4096, 256, 0, stream>>>(zp, cp, ws + WS_ZNORM, ws + WS_ENORM, slab1, slab2);
    refine_gather_kernel<<<2048, 256, 0, stream>>>(z, cb, ws + WS_ZNORM, ws + WS_ENORM,
                                                   slab1, slab2, out, icount, lossP);
    scan_ncs_scatter_kernel<<<1, 256, 0, stream>>>(icount, cs, lossP, out + IDX_OFF,
                                                   offsB, list, out, nsum);
    if (wsbig) {
        percode_finalize_kernel<<<8192, 256, 0, stream>>>(z, ea, list, offsB, icount, out, nsum);
    } else {
        percode_sum_kernel<<<8192, 256, 0, stream>>>(z, list, offsB, icount, out);
        finalize_kernel<<<8192, 256, 0, stream>>>(ea, out, nsum);
    }
}